// Round 11
// baseline (868.965 us; speedup 1.0000x reference)
//
#include <hip/hip_runtime.h>
#include <hip/hip_bf16.h>
#include <stdint.h>

#define B_   16
#define C_   512
#define T_   2048
#define O_   512

#define BNO  128         // T output tile
#define BNE  144         // T ext tile (halo 8 each side)
#define QS   148         // epilogue f32 row stride

// LDS half-offsets (image layout == LDS layout); BM=128 -> 384 W rows (3 mats x 128)
#define WLO_OFF 15360    // 384*40
#define XHI_OFF 30720    // 2*384*40
#define LDS_HALVES 36864 // 73,728 B (72 KiB staged incl. 768 B dead X tail)

#define WCHUNK 61440u    // bytes per (ob,kc) W image chunk (2 planes * 384 rows * 80 B)
#define XCHUNK 12288u    // bytes per (b,tb,kc) X image chunk (144*80 B data + 768 pad)
#define WIMG_BYTES (64ull * WCHUNK)      // 3,932,160  (4 ob * 16 kc)
#define XIMG_BYTES (4096ull * XCHUNK)    // 50,331,648 (16 b * 16 tb * 16 kc)

typedef _Float16 half4_t __attribute__((ext_vector_type(4)));
typedef _Float16 half8_t __attribute__((ext_vector_type(8)));
typedef float    f32x4   __attribute__((ext_vector_type(4)));

__device__ __forceinline__ void load_lds16(const void* g, void* l) {
  __builtin_amdgcn_global_load_lds(
      (const __attribute__((address_space(1))) uint32_t*)g,
      (__attribute__((address_space(3))) uint32_t*)l, 16, 0, 0);
}

// ---------- pack W image: [ob=4][kc=16][pl=2][384 rows][40 halves], W scaled x64 ----------
__global__ __launch_bounds__(256) void pack_w_img(
    const float* __restrict__ wq, const float* __restrict__ wk,
    const float* __restrict__ wv, _Float16* __restrict__ wimg) {
  int t = blockIdx.x * 256 + threadIdx.x;     // 491,520 tasks (half4 each)
  int j4  = t % 10;
  int rem = t / 10;                           // 0..49151
  int row = rem % 384;
  int pl  = (rem / 384) & 1;
  int kc  = (rem / 768) & 15;
  int ob  = rem / 12288;                      // 0..3
  const float* src = (row < 128) ? wq : (row < 256) ? wk : wv;
  int r = row & 127;
  half4_t o4 = {(_Float16)0, (_Float16)0, (_Float16)0, (_Float16)0};
  if (j4 < 8) {
    const float* p = src + ((size_t)(ob * 128 + r)) * 512 + kc * 32 + j4 * 4;
    float4 v = *reinterpret_cast<const float4*>(p);
    float vv[4] = {v.x, v.y, v.z, v.w};
#pragma unroll
    for (int e = 0; e < 4; ++e) {
      float s = vv[e] * 64.0f;                // keep wlo out of f16 subnormals
      _Float16 hi = (_Float16)s;
      o4[e] = pl ? (_Float16)(s - (float)hi) : hi;
    }
  }
  *reinterpret_cast<half4_t*>(wimg + ((size_t)(ob * 16 + kc)) * 30720 +
                              pl * 15360 + row * 40 + j4 * 4) = o4;
}

// ---------- pack X image: [b=16][tb=16][kc=16][144 rows(t)][40 halves(k)], f16 ----------
// (unchanged from R10) 2 kc per block: grid (8, 16, 16)
__global__ __launch_bounds__(256) void pack_x_img(
    const float* __restrict__ x, _Float16* __restrict__ ximg) {
  __shared__ float tile[64 * 145];
  const int bx = blockIdx.x, tb = blockIdx.y, b = blockIdx.z;
  const int tid = threadIdx.x;
  const int tbase = tb * BNO - 8;
  const int cb = bx * 64;                       // channels for kc = 2bx, 2bx+1
  const float* xb = x + ((size_t)b * 512 + cb) * 2048;
#pragma unroll
  for (int it = 0; it < 9; ++it) {
    int task = it * 256 + tid;                  // 2304 float4 tasks
    int c = task / 36, f4 = task % 36;
    int t0 = tbase + f4 * 4;
    float* dst = tile + c * 145 + f4 * 4;
    if (t0 >= 0 && t0 + 3 < 2048) {
      float4 v4 = *reinterpret_cast<const float4*>(xb + (size_t)c * 2048 + t0);
      dst[0] = v4.x; dst[1] = v4.y; dst[2] = v4.z; dst[3] = v4.w;
    } else {
#pragma unroll
      for (int e = 0; e < 4; ++e) {
        int tg = t0 + e;
        dst[e] = ((unsigned)tg < 2048u) ? xb[(size_t)c * 2048 + tg] : 0.0f;
      }
    }
  }
  __syncthreads();
  _Float16* dst0 = ximg + ((size_t)((b * 16 + tb) * 16 + 2 * bx)) * 6144;
#pragma unroll
  for (int it = 0; it < 12; ++it) {
    int task = it * 256 + tid;                  // 2880 half4 tasks
    if (task < 2880) {
      int kk = task / 1440;
      int r = task - kk * 1440;
      int j4 = r % 10;
      int rw = r / 10;                          // 0..143
      half4_t o4 = {(_Float16)0, (_Float16)0, (_Float16)0, (_Float16)0};
      if (j4 < 8) {
#pragma unroll
        for (int e = 0; e < 4; ++e)
          o4[e] = (_Float16)tile[(kk * 32 + j4 * 4 + e) * 145 + rw];
      }
      *reinterpret_cast<half4_t*>(dst0 + (size_t)kk * 6144 + rw * 40 + j4 * 4) = o4;
    }
  }
}

// ---------- fallback W pack: plain [3][O][C] hi/lo planes, scaled x64 ----------
__global__ __launch_bounds__(256) void pack_w_plain(
    const float* __restrict__ wq, const float* __restrict__ wk,
    const float* __restrict__ wv, _Float16* __restrict__ whi,
    _Float16* __restrict__ wlo) {
  int gid = blockIdx.x * 256 + threadIdx.x;
  int idx = gid * 4;
  int m = idx >> 18;
  int rem = idx & 262143;
  const float* src = (m == 0) ? wq : (m == 1) ? wk : wv;
  float4 xv = *reinterpret_cast<const float4*>(src + rem);
  float xs[4] = {xv.x, xv.y, xv.z, xv.w};
  half4_t h, l;
#pragma unroll
  for (int e = 0; e < 4; ++e) {
    float s = xs[e] * 64.0f;
    _Float16 hi = (_Float16)s;
    h[e] = hi;
    l[e] = (_Float16)(s - (float)hi);
  }
  *reinterpret_cast<half4_t*>(whi + (size_t)m * 262144 + rem) = h;
  *reinterpret_cast<half4_t*>(wlo + (size_t)m * 262144 + rem) = l;
}

// ---------- fused QKV GEMM (2-term f16 split MFMA) + 3-tap softmax ----------
// 1024 blocks x 512 threads (8 waves). Block = 128 o-rows x 128 t-cols.
// XCD swizzle keeps the 4 ob-blocks of one (b,tb) adjacent (same XCD L2).
template <int MODE>
__global__ __launch_bounds__(512, 4) void fused_kernel(
    const float* __restrict__ x,
    const _Float16* __restrict__ wA,    // MODE1: wimg ; MODE0: whi plain
    const _Float16* __restrict__ wB,    // MODE0: wlo plain
    const _Float16* __restrict__ ximg,  // MODE1 only
    float* __restrict__ out) {
  __shared__ __align__(16) _Float16 smem[LDS_HALVES];
  const int tid = threadIdx.x;
  const int flat = blockIdx.x;
  const int work = (flat & 7) * 128 + (flat >> 3);  // 1024 % 8 == 0 -> bijective
  const int ob = work & 3;
  const int g  = work >> 2;               // 0..255
  const int tb = g & 15;
  const int b  = g >> 4;
  const int obase = ob * 128;
  const int lane = tid & 63, w = tid >> 6;      // 8 waves
  const int lr = lane & 15, lg = lane >> 4;

  f32x4 acc[3][9];
#pragma unroll
  for (int m = 0; m < 3; ++m)
#pragma unroll
    for (int n = 0; n < 9; ++n) acc[m][n] = {0.f, 0.f, 0.f, 0.f};

  const char* wsrc = nullptr;
  const char* xsrc = nullptr;
  if constexpr (MODE == 1) {
    wsrc = (const char*)wA + (size_t)(ob * 16) * WCHUNK;
    xsrc = (const char*)ximg + (size_t)((b * 16 + tb) * 16) * XCHUNK;
  }

  // one K-step's 72 KiB image -> LDS, pure DMA: 72 chunks = 9 rounds x 8 waves
  auto issue_stage = [&](int kc) {
#pragma unroll
    for (int it = 0; it < 9; ++it) {
      int j = it * 8 + w;                  // wave-uniform, 0..71 exact
      const char* src = (j < 60) ? (wsrc + (size_t)kc * WCHUNK + (size_t)j * 1024)
                                 : (xsrc + (size_t)kc * XCHUNK + (size_t)(j - 60) * 1024);
      load_lds16(src + lane * 16, (char*)smem + (size_t)j * 1024);
    }
  };

  if constexpr (MODE == 1) issue_stage(0);

  for (int kc = 0; kc < 16; ++kc) {
    if constexpr (MODE == 1) {
      __syncthreads();  // drains vmcnt(0): stage(kc) landed, all waves
    } else {
      __syncthreads();
      const int k0 = kc * 32;
      // W stage: b128 copies from pre-split planes (3072 16B-chunks)
#pragma unroll
      for (int it = 0; it < 6; ++it) {
        int c = it * 512 + tid;
        int pl = (c >= 1536) ? 1 : 0;
        int cc = c - pl * 1536;
        int r = cc >> 2, q = cc & 3;         // r 0..383
        int m = r >> 7, rr = r & 127;
        const _Float16* sp = (pl ? wB : wA) +
            ((size_t)(m * 512 + obase + rr)) * 512 + k0 + q * 8;
        half8_t v = *reinterpret_cast<const half8_t*>(sp);
        *reinterpret_cast<half8_t*>(smem + pl * 15360 + r * 40 + q * 8) = v;
      }
      // X stage on the fly: single f16 plane, 144 t x 32 k (1152 tasks)
      const int tbase = tb * BNO - 8;
#pragma unroll
      for (int it = 0; it < 3; ++it) {
        int task = it * 512 + tid;
        if (task < 1152) {
          int t = task >> 3;
          int k4 = task & 7;
          int tg = tbase + t;
          bool ok = (unsigned)tg < 2048u;
          const float* px = x + ((size_t)b * 512 + k0 + k4 * 4) * 2048 + tg;
          half4_t h4;
#pragma unroll
          for (int e = 0; e < 4; ++e)
            h4[e] = (_Float16)(ok ? px[(size_t)e * 2048] : 0.0f);
          *reinterpret_cast<half4_t*>(smem + XHI_OFF + t * 40 + k4 * 4) = h4;
        }
      }
      __syncthreads();
    }

    // ---- fragment loads (b128): LDS(kc) -> VGPRs ----
    half8_t ahi[3], alo[3], bhi[9];
#pragma unroll
    for (int m = 0; m < 3; ++m) {
      int off = (m * 128 + 16 * w + lr) * 40 + lg * 8;
      ahi[m] = *reinterpret_cast<const half8_t*>(smem + off);
      alo[m] = *reinterpret_cast<const half8_t*>(smem + WLO_OFF + off);
    }
#pragma unroll
    for (int n = 0; n < 9; ++n) {
      int off = (16 * n + lr) * 40 + lg * 8;
      bhi[n] = *reinterpret_cast<const half8_t*>(smem + XHI_OFF + off);
    }

    if constexpr (MODE == 1) {
      __syncthreads();                     // all waves' frag reads done (lgkm drained)
      if (kc != 15) issue_stage(kc + 1);   // DMA for next step overlaps MFMA below
    }

    __builtin_amdgcn_s_setprio(1);
#pragma unroll
    for (int m = 0; m < 3; ++m)
#pragma unroll
      for (int n = 0; n < 9; ++n) {
        acc[m][n] = __builtin_amdgcn_mfma_f32_16x16x32_f16(ahi[m], bhi[n], acc[m][n], 0, 0, 0);
        acc[m][n] = __builtin_amdgcn_mfma_f32_16x16x32_f16(alo[m], bhi[n], acc[m][n], 0, 0, 0);
      }
    __builtin_amdgcn_s_setprio(0);
  }

  // ---- epilogue: 4 passes of 32 o-rows (wave pairs), QKV [3*32][QS] f32 ----
  const float SC_S = 1.0f / 4096.0f;  // scores carry 64^2 from W scaling
  const float SC_V = 1.0f / 64.0f;
  float* QKV = (float*)smem;          // 3*32*148*4 = 56,832 B < 73,728
  const int colL = tid & 127;
  const int rh = tid >> 7;            // 0..3
  float* outB = out + ((size_t)b * 512 + obase) * 2048 + tb * BNO;
#pragma unroll
  for (int pass = 0; pass < 4; ++pass) {
    __syncthreads();  // frag/MFMA LDS reads (pass0) / prev-pass reads complete
    if ((w >> 1) == pass) {
      int wsub = w & 1;
#pragma unroll
      for (int m = 0; m < 3; ++m)
#pragma unroll
        for (int n = 0; n < 9; ++n)
#pragma unroll
          for (int i = 0; i < 4; ++i)
            QKV[(m * 32 + 16 * wsub + 4 * lg + i) * QS + 16 * n + lr] = acc[m][n][i];
    }
    __syncthreads();
#pragma unroll
    for (int it = 0; it < 8; ++it) {
      int r = it * 4 + rh;  // 0..31
      const float* q_ = QKV + r * QS + 8 + colL;
      const float* k_ = QKV + (32 + r) * QS + 8 + colL;
      const float* v_ = QKV + (64 + r) * QS + 8 + colL;
      float q = q_[0];
      float s0 = q * k_[-4] * SC_S;
      float s1 = q * k_[0] * SC_S;
      float s2 = q * k_[4] * SC_S;
      float mx = fmaxf(fmaxf(s0, s1), s2);
      float e0 = __expf(s0 - mx), e1 = __expf(s1 - mx), e2 = __expf(s2 - mx);
      float o = (e0 * v_[-4] + e1 * v_[0] + e2 * v_[4]) * (SC_V / (e0 + e1 + e2));
      outB[((size_t)(32 * pass + r)) * 2048 + colL] = o;
    }
  }
}

extern "C" void kernel_launch(void* const* d_in, const int* in_sizes, int n_in,
                              void* d_out, int out_size, void* d_ws, size_t ws_size,
                              hipStream_t stream) {
  (void)in_sizes; (void)n_in; (void)out_size;
  const float* x = (const float*)d_in[0];
  const float* wq = (const float*)d_in[1];
  const float* wk = (const float*)d_in[2];
  const float* wv = (const float*)d_in[3];
  float* out = (float*)d_out;

  if (ws_size >= WIMG_BYTES + XIMG_BYTES) {   // 54.3 MB (ws proven >= 113 MB in R4/R9)
    _Float16* wimg = (_Float16*)d_ws;
    _Float16* ximg = (_Float16*)((char*)d_ws + WIMG_BYTES);
    pack_w_img<<<1920, 256, 0, stream>>>(wq, wk, wv, wimg);
    pack_x_img<<<dim3(8, 16, 16), 256, 0, stream>>>(x, ximg);
    fused_kernel<1><<<1024, 512, 0, stream>>>(x, wimg, nullptr, ximg, out);
  } else {
    _Float16* whi = (_Float16*)d_ws;   // needs >= 3 MiB
    _Float16* wlo = whi + 3 * 262144;
    pack_w_plain<<<768, 256, 0, stream>>>(wq, wk, wv, whi, wlo);
    fused_kernel<0><<<1024, 512, 0, stream>>>(x, whi, wlo, nullptr, out);
  }
}